// Round 4
// baseline (198.452 us; speedup 1.0000x reference)
//
#include <hip/hip_runtime.h>

// MPS tensor-train classifier, B=16384, D=784, BOND=5, OUT=10.
//
// res[b] = carry0(x0) . (prod_{m=0..781} M_m(x[m+1])) . vlast(x783)
// Pair p (sites 2p+1, 2p+2):  C_p = P0 + xa*P1 + xb*P2 + xa*xb*P3
// (P0=A0A0', P1=NA0', P2=A0N', P3=NN' prepacked; N = A1-A0).
// Pairs >= BWD_P0 stored TRANSPOSED so the bwd wave uses row-vector code.
//
// Round-4: NO LDS round-trip for pk (round 3's DS pipe was saturated:
// 16 waves x 22 pairs x 28 ds_read_b128 per CU ~ the whole runtime).
// Pair blocks are wave-uniform -> read direct from global (compiler emits
// s_load on the SMEM pipe: zero VALU, zero DS). All math on native v2f for
// v_pk_fma_f32. Single barrier; matbuf holds all 14 segment matrices.
//
// 256 blocks x 1024 thr (16 waves), lane = batch row:
//   wave 0    : fwd vector chain (site 0 + pairs 0..40), combine, output
//   waves 1-14: 22-pair 5x5 matrix products (pairs 41..348)
//   wave 15   : bwd vector chain (site 781 + pairs 389..349 desc)

typedef float v2f __attribute__((ext_vector_type(2)));

constexpr int Bn     = 16384;
constexpr int Dn     = 784;
constexpr int NOUT   = 10;
constexpr int NPAIR  = 390;   // pairs cover sites 1..780
constexpr int PFV    = 41;    // fwd pairs 0..40
constexpr int PMAT   = 22;    // pairs per matrix wave (14 waves: 41..348)
constexpr int BWD_P0 = 349;   // bwd pairs 349..389 (stored transposed)
constexpr int PKP    = 128;   // floats per pair block: 4 mats x 32 (512 B)
// per-mat layout (32 floats): row l occupies 6*l .. 6*l+4 (a=+0, b=+2, e=+4),
// floats 30..31 pad. Mat q at offset q*32 (q: 0=P0, 1=P1(xa), 2=P2(xb), 3=P3).

__device__ __forceinline__ v2f fma2(v2f a, v2f b, v2f c) {
    return __builtin_elementwise_fma(a, b, c);
}
__device__ __forceinline__ v2f sp2(float x) { v2f v = {x, x}; return v; }

struct R5 { v2f a, b; float e; };   // one 5-wide row

// C = P0 + xa*P1 + xb*P2 + xa*xb*P3   (45 pk/scalar fma + 1 mul)
__device__ __forceinline__ void buildC(const float* __restrict__ s,
                                       float xa, float xb, R5 C[5]) {
    const float xab = xa * xb;
    const v2f va = sp2(xa), vb = sp2(xb), vab = sp2(xab);
#pragma unroll
    for (int l = 0; l < 5; ++l) {
        const float* r = s + 6 * l;
        v2f a = *(const v2f*)(r);
        v2f b = *(const v2f*)(r + 2);
        float e = r[4];
        a = fma2(va,  *(const v2f*)(r + 32), a);
        b = fma2(va,  *(const v2f*)(r + 34), b);
        e = fmaf(xa,  r[36], e);
        a = fma2(vb,  *(const v2f*)(r + 64), a);
        b = fma2(vb,  *(const v2f*)(r + 66), b);
        e = fmaf(xb,  r[68], e);
        a = fma2(vab, *(const v2f*)(r + 96), a);
        b = fma2(vab, *(const v2f*)(r + 98), b);
        e = fmaf(xab, r[100], e);
        C[l].a = a; C[l].b = b; C[l].e = e;
    }
}

// t = s @ C   (row 5-vector times 5x5; 10 pk + 5 scalar)
__device__ __forceinline__ R5 rowmul(const R5& s, const R5 C[5]) {
    R5 t;
    float m = s.a[0];
    t.a = sp2(m) * C[0].a; t.b = sp2(m) * C[0].b; t.e = m * C[0].e;
    m = s.a[1];
    t.a = fma2(sp2(m), C[1].a, t.a); t.b = fma2(sp2(m), C[1].b, t.b); t.e = fmaf(m, C[1].e, t.e);
    m = s.b[0];
    t.a = fma2(sp2(m), C[2].a, t.a); t.b = fma2(sp2(m), C[2].b, t.b); t.e = fmaf(m, C[2].e, t.e);
    m = s.b[1];
    t.a = fma2(sp2(m), C[3].a, t.a); t.b = fma2(sp2(m), C[3].b, t.b); t.e = fmaf(m, C[3].e, t.e);
    m = s.e;
    t.a = fma2(sp2(m), C[4].a, t.a); t.b = fma2(sp2(m), C[4].b, t.b); t.e = fmaf(m, C[4].e, t.e);
    return t;
}

// ---- prepack: pair blocks (transposed for p >= BWD_P0) ----
// cores_mid element (m,l,i,k) at (m*5+l)*10 + i*5 + k
__global__ void prepack_pairs(const float* __restrict__ cm, float* __restrict__ pk)
{
    int idx = blockIdx.x * 256 + threadIdx.x;
    if (idx >= NPAIR * 100) return;
    int p = idx / 100, rest = idx - p * 100;
    int q = rest / 25, e = rest - q * 25;
    int l = e / 5, r = e - l * 5;
    int m1 = 2 * p + 1, m2 = 2 * p + 2;
    const float* L = cm + (size_t)(m1 * 5 + l) * 10;
    float acc = 0.f;
#pragma unroll
    for (int k = 0; k < 5; ++k) {
        float Lk = (q & 1) ? (L[5 + k] - L[k]) : L[k];
        const float* R = cm + (size_t)(m2 * 5 + k) * 10;
        float Rk = (q & 2) ? (R[5 + r] - R[r]) : R[r];
        acc = fmaf(Lk, Rk, acc);
    }
    int wl = l, wr = r;
    if (p >= BWD_P0) { wl = r; wr = l; }   // store C^T for the bwd wave
    pk[(size_t)p * PKP + q * 32 + wl * 6 + wr] = acc;
}

__global__ __launch_bounds__(1024)
void mps_pair_sload_kernel(const float* __restrict__ x,          // [B, D]
                           const float* __restrict__ core_first, // [2,5]
                           const float* __restrict__ cores_mid,  // [782,5,2,5]
                           const float* __restrict__ core_last,  // [5,2]
                           const float* __restrict__ fc_w,       // [10]
                           const float* __restrict__ fc_b,       // [10]
                           const float* __restrict__ pk,         // [390][128]
                           float* __restrict__ out)              // [B,10]
{
    __shared__ float matbuf[14][25][64];  // 89.6 KB: all segment matrices
    __shared__ float bv[5][64];           // backward vectors

    const int lane = threadIdx.x & 63;
    const int wave = threadIdx.x >> 6;
    const int row  = blockIdx.x * 64 + lane;
    const float* __restrict__ xr = x + (size_t)row * Dn;
    const v2f* __restrict__ xr2 = (const v2f*)xr;   // 392 entries

    R5 fc;   // wave-0 forward carry, live across the barrier

    if (wave >= 1 && wave <= 14) {
        // ---- matrix wave: 22-pair 5x5 product, ping-pong M/T ----
        const int p0 = PFV + PMAT * (wave - 1);
        R5 M[5], T[5], C[5];
        M[0] = {{1.f, 0.f}, {0.f, 0.f}, 0.f};
        M[1] = {{0.f, 1.f}, {0.f, 0.f}, 0.f};
        M[2] = {{0.f, 0.f}, {1.f, 0.f}, 0.f};
        M[3] = {{0.f, 0.f}, {0.f, 1.f}, 0.f};
        M[4] = {{0.f, 0.f}, {0.f, 0.f}, 1.f};
#pragma unroll 1
        for (int i = 0; i < PMAT / 2; ++i) {
            const int p = p0 + 2 * i;
            const v2f x1 = xr2[p + 1];            // {x[2p+2], x[2p+3]}
            const v2f x2 = xr2[p + 2];
            buildC(pk + (size_t)p * PKP, x1[0], x1[1], C);
#pragma unroll
            for (int r = 0; r < 5; ++r) T[r] = rowmul(M[r], C);
            buildC(pk + (size_t)(p + 1) * PKP, x2[0], x2[1], C);
#pragma unroll
            for (int r = 0; r < 5; ++r) M[r] = rowmul(T[r], C);
        }
#pragma unroll
        for (int r = 0; r < 5; ++r) {
            matbuf[wave - 1][r * 5 + 0][lane] = M[r].a[0];
            matbuf[wave - 1][r * 5 + 1][lane] = M[r].a[1];
            matbuf[wave - 1][r * 5 + 2][lane] = M[r].b[0];
            matbuf[wave - 1][r * 5 + 3][lane] = M[r].b[1];
            matbuf[wave - 1][r * 5 + 4][lane] = M[r].e;
        }
    } else if (wave == 0) {
        // ---- forward: carry0, site 0 (scalar), pairs 0..40 ----
        const v2f x01 = xr2[0];
        float cl[5], cn[5];
#pragma unroll
        for (int r = 0; r < 5; ++r)
            cl[r] = fmaf(x01[0], core_first[5 + r] - core_first[r], core_first[r]);
        const float* cm0 = cores_mid;             // site m=0
#pragma unroll
        for (int r = 0; r < 5; ++r) {
            float a = 0.f;
#pragma unroll
            for (int l = 0; l < 5; ++l) {
                float mm = fmaf(x01[1], cm0[l * 10 + 5 + r] - cm0[l * 10 + r],
                                cm0[l * 10 + r]);
                a = fmaf(cl[l], mm, a);
            }
            cn[r] = a;
        }
        fc.a = {cn[0], cn[1]}; fc.b = {cn[2], cn[3]}; fc.e = cn[4];
        R5 C[5];
#pragma unroll 1
        for (int p = 0; p < PFV; ++p) {
            const v2f xv = xr2[p + 1];
            buildC(pk + (size_t)p * PKP, xv[0], xv[1], C);
            fc = rowmul(fc, C);
        }
    } else {
        // ---- backward: vlast, site 781 (scalar), pairs 389..349 desc ----
        const v2f xz = xr2[391];                  // {x[782], x[783]}
        float vl[5], vn[5];
#pragma unroll
        for (int l = 0; l < 5; ++l)
            vl[l] = fmaf(xz[1], core_last[2 * l + 1] - core_last[2 * l],
                         core_last[2 * l]);
        const float* cmL = cores_mid + (size_t)781 * 50;   // site m=781
#pragma unroll
        for (int l = 0; l < 5; ++l) {
            float a = 0.f;
#pragma unroll
            for (int r = 0; r < 5; ++r) {
                float mm = fmaf(xz[0], cmL[l * 10 + 5 + r] - cmL[l * 10 + r],
                                cmL[l * 10 + r]);
                a = fmaf(mm, vl[r], a);
            }
            vn[l] = a;
        }
        R5 u; u.a = {vn[0], vn[1]}; u.b = {vn[2], vn[3]}; u.e = vn[4];
        R5 C[5];
#pragma unroll 1
        for (int p = NPAIR - 1; p >= BWD_P0; --p) {
            const v2f xv = xr2[p + 1];
            buildC(pk + (size_t)p * PKP, xv[0], xv[1], C);
            u = rowmul(u, C);          // stored C^T -> row form of column chain
        }
        bv[0][lane] = u.a[0]; bv[1][lane] = u.a[1];
        bv[2][lane] = u.b[0]; bv[3][lane] = u.b[1];
        bv[4][lane] = u.e;
    }

    __syncthreads();

    if (wave == 0) {
        // ---- combine: fc @ (seg1 .. seg14) . bv, then fc layer ----
        float cl[5] = {fc.a[0], fc.a[1], fc.b[0], fc.b[1], fc.e};
#pragma unroll 1
        for (int w2 = 0; w2 < 14; ++w2) {
            float v0[5];
#pragma unroll
            for (int r = 0; r < 5; ++r) v0[r] = cl[0] * matbuf[w2][r][lane];
#pragma unroll
            for (int l = 1; l < 5; ++l)
#pragma unroll
                for (int r = 0; r < 5; ++r)
                    v0[r] = fmaf(cl[l], matbuf[w2][l * 5 + r][lane], v0[r]);
#pragma unroll
            for (int r = 0; r < 5; ++r) cl[r] = v0[r];
        }
        float res = 0.f;
#pragma unroll
        for (int l = 0; l < 5; ++l) res = fmaf(cl[l], bv[l][lane], res);
        float* orow = out + (size_t)row * NOUT;
#pragma unroll
        for (int o = 0; o < NOUT; ++o) orow[o] = fmaf(res, fc_w[o], fc_b[o]);
    }
}

extern "C" void kernel_launch(void* const* d_in, const int* in_sizes, int n_in,
                              void* d_out, int out_size, void* d_ws, size_t ws_size,
                              hipStream_t stream) {
    const float* x          = (const float*)d_in[0];
    const float* core_first = (const float*)d_in[1];
    const float* cores_mid  = (const float*)d_in[2];
    const float* core_last  = (const float*)d_in[3];
    const float* fc_w       = (const float*)d_in[4];
    const float* fc_b       = (const float*)d_in[5];
    float* out              = (float*)d_out;
    float* pk               = (float*)d_ws;   // 390*128*4 = 199,680 B

    hipLaunchKernelGGL(prepack_pairs, dim3((NPAIR * 100 + 255) / 256), dim3(256),
                       0, stream, cores_mid, pk);
    hipLaunchKernelGGL(mps_pair_sload_kernel, dim3(Bn / 64), dim3(1024), 0, stream,
                       x, core_first, cores_mid, core_last, fc_w, fc_b, pk, out);
}

// Round 5
// 145.666 us; speedup vs baseline: 1.3624x; 1.3624x over previous
//
#include <hip/hip_runtime.h>

// MPS tensor-train classifier, B=16384, D=784, BOND=5, OUT=10.
//
// res[b] = carry0(x0) . (prod_{m=0..781} M_m(x[m+1])) . vlast(x783)
// Pair p (sites 2p+1, 2p+2):  C_p = P0 + xa*P1 + xb*P2 + xa*xb*P3
// (P0=A0A0', P1=NA0', P2=A0N', P3=NN' prepacked; N = A1-A0).
// Pairs >= BWD_P0 stored TRANSPOSED so the bwd wave uses row-vector code.
//
// Round-5 vs round-4 (which spilled: WRITE_SIZE 89 MB of scratch):
//  * readfirstlane(wave) -> pk addresses provably uniform -> s_load (SMEM
//    pipe, SGPR dest). No DS traffic (round-3 bug), no VGPR load staging
//    (round-4 bug).
//  * in-place row update M[r] = rowmul(M[r], C): kills the 25-float T temp.
//  * __launch_bounds__(1024, 4): VGPR cap 128 (16 waves/CU), stops the
//    64-VGPR heuristic that caused the spill.
//  * e-column packed as v2f: mat pair 121 -> 110 instr, vec pair 61 -> 54.
//
// 256 blocks x 1024 thr (16 waves), lane = batch row:
//   wave 0    : fwd vector chain (site 0 + pairs 0..40), combine, output
//   waves 1-14: 22-pair 5x5 matrix products (pairs 41..348)
//   wave 15   : bwd vector chain (site 781 + pairs 389..349 desc)

typedef float v2f __attribute__((ext_vector_type(2)));

constexpr int Bn     = 16384;
constexpr int Dn     = 784;
constexpr int NOUT   = 10;
constexpr int NPAIR  = 390;   // pairs cover sites 1..780
constexpr int PFV    = 41;    // fwd pairs 0..40
constexpr int PMAT   = 22;    // pairs per matrix wave (14 waves: 41..348)
constexpr int BWD_P0 = 349;   // bwd pairs 349..389 (stored transposed)
constexpr int PKP    = 112;   // floats per pair block: 4 mats x 28 (448 B)
// per-mat layout (28 floats): element (l,r) r<4 at l*4+r; col-4 (l,4) at 20+l;
// pad 25..27. Mat q at offset q*28 (q: 0=P0, 1=P1(xa), 2=P2(xb), 3=P3).

__device__ __forceinline__ v2f fma2(v2f a, v2f b, v2f c) {
    return __builtin_elementwise_fma(a, b, c);
}
__device__ __forceinline__ v2f sp2(float x) { v2f v = {x, x}; return v; }

struct R5 { v2f a, b; float e; };                      // one 5-wide row
struct C5 { v2f a[5], b[5], e01, e23; float e4; };     // 5x5 pair matrix

// C = P0 + xa*P1 + xb*P2 + xa*xb*P3   (39 fma + 1 mul)
__device__ __forceinline__ void buildC(const float* __restrict__ s,
                                       float xa, float xb, C5& C) {
    const float xab = xa * xb;
    const v2f va = sp2(xa), vb = sp2(xb), vab = sp2(xab);
#pragma unroll
    for (int l = 0; l < 5; ++l) {
        v2f a = *(const v2f*)(s + 4 * l);
        a = fma2(va,  *(const v2f*)(s + 28 + 4 * l), a);
        a = fma2(vb,  *(const v2f*)(s + 56 + 4 * l), a);
        a = fma2(vab, *(const v2f*)(s + 84 + 4 * l), a);
        C.a[l] = a;
        v2f b = *(const v2f*)(s + 4 * l + 2);
        b = fma2(va,  *(const v2f*)(s + 30 + 4 * l), b);
        b = fma2(vb,  *(const v2f*)(s + 58 + 4 * l), b);
        b = fma2(vab, *(const v2f*)(s + 86 + 4 * l), b);
        C.b[l] = b;
    }
    v2f e01 = *(const v2f*)(s + 20);
    e01 = fma2(va,  *(const v2f*)(s + 48),  e01);
    e01 = fma2(vb,  *(const v2f*)(s + 76),  e01);
    e01 = fma2(vab, *(const v2f*)(s + 104), e01);
    C.e01 = e01;
    v2f e23 = *(const v2f*)(s + 22);
    e23 = fma2(va,  *(const v2f*)(s + 50),  e23);
    e23 = fma2(vb,  *(const v2f*)(s + 78),  e23);
    e23 = fma2(vab, *(const v2f*)(s + 106), e23);
    C.e23 = e23;
    C.e4 = fmaf(xab, s[108], fmaf(xb, s[80], fmaf(xa, s[52], s[24])));
}

// t = s @ C   (row 5-vector times 5x5; 12 pk + 1 add + 1 fma)
__device__ __forceinline__ R5 rowmul(const R5& s, const C5& C) {
    R5 t;
    t.a = sp2(s.a[0]) * C.a[0];
    t.b = sp2(s.a[0]) * C.b[0];
    t.a = fma2(sp2(s.a[1]), C.a[1], t.a); t.b = fma2(sp2(s.a[1]), C.b[1], t.b);
    t.a = fma2(sp2(s.b[0]), C.a[2], t.a); t.b = fma2(sp2(s.b[0]), C.b[2], t.b);
    t.a = fma2(sp2(s.b[1]), C.a[3], t.a); t.b = fma2(sp2(s.b[1]), C.b[3], t.b);
    t.a = fma2(sp2(s.e),    C.a[4], t.a); t.b = fma2(sp2(s.e),    C.b[4], t.b);
    v2f acc = s.a * C.e01;
    acc = fma2(s.b, C.e23, acc);
    t.e = fmaf(s.e, C.e4, acc[0] + acc[1]);
    return t;
}

// ---- prepack: pair blocks (transposed for p >= BWD_P0) ----
// cores_mid element (m,l,i,k) at (m*5+l)*10 + i*5 + k
__global__ void prepack_pairs(const float* __restrict__ cm, float* __restrict__ pk)
{
    int idx = blockIdx.x * 256 + threadIdx.x;
    if (idx >= NPAIR * 100) return;
    int p = idx / 100, rest = idx - p * 100;
    int q = rest / 25, e = rest - q * 25;
    int l = e / 5, r = e - l * 5;
    int m1 = 2 * p + 1, m2 = 2 * p + 2;
    const float* L = cm + (size_t)(m1 * 5 + l) * 10;
    float acc = 0.f;
#pragma unroll
    for (int k = 0; k < 5; ++k) {
        float Lk = (q & 1) ? (L[5 + k] - L[k]) : L[k];
        const float* R = cm + (size_t)(m2 * 5 + k) * 10;
        float Rk = (q & 2) ? (R[5 + r] - R[r]) : R[r];
        acc = fmaf(Lk, Rk, acc);
    }
    int wl = l, wr = r;
    if (p >= BWD_P0) { wl = r; wr = l; }   // store C^T for the bwd wave
    int off = (wr < 4) ? (wl * 4 + wr) : (20 + wl);
    pk[(size_t)p * PKP + q * 28 + off] = acc;
}

__global__ __launch_bounds__(1024, 4)
void mps_pair_smem_kernel(const float* __restrict__ x,          // [B, D]
                          const float* __restrict__ core_first, // [2,5]
                          const float* __restrict__ cores_mid,  // [782,5,2,5]
                          const float* __restrict__ core_last,  // [5,2]
                          const float* __restrict__ fc_w,       // [10]
                          const float* __restrict__ fc_b,       // [10]
                          const float* __restrict__ pk,         // [390][112]
                          float* __restrict__ out)              // [B,10]
{
    __shared__ float matbuf[14][25][64];  // 89.6 KB: all segment matrices
    __shared__ float bv[5][64];           // backward vectors

    const int lane = threadIdx.x & 63;
    // readfirstlane: segment id is PROVABLY uniform -> pk loads scalarize
    const int wseg = __builtin_amdgcn_readfirstlane(threadIdx.x >> 6);
    const int row  = blockIdx.x * 64 + lane;
    const float* __restrict__ xr = x + (size_t)row * Dn;
    const v2f* __restrict__ xr2 = (const v2f*)xr;   // 392 entries

    R5 fc;   // wave-0 forward carry, live across the barrier

    if (wseg >= 1 && wseg <= 14) {
        // ---- matrix wave: 22-pair 5x5 product, in-place row updates ----
        const int p0 = PFV + PMAT * (wseg - 1);
        const float* __restrict__ s = pk + (size_t)p0 * PKP;
        R5 M[5];
        M[0] = {{1.f, 0.f}, {0.f, 0.f}, 0.f};
        M[1] = {{0.f, 1.f}, {0.f, 0.f}, 0.f};
        M[2] = {{0.f, 0.f}, {1.f, 0.f}, 0.f};
        M[3] = {{0.f, 0.f}, {0.f, 1.f}, 0.f};
        M[4] = {{0.f, 0.f}, {0.f, 0.f}, 1.f};
        C5 C;
#pragma unroll 1
        for (int i = 0; i < PMAT; ++i) {
            const v2f xv = xr2[p0 + i + 1];       // {x[2p+1+1], x[2p+2+1]}
            buildC(s, xv[0], xv[1], C);
#pragma unroll
            for (int r = 0; r < 5; ++r) M[r] = rowmul(M[r], C);
            s += PKP;
        }
#pragma unroll
        for (int r = 0; r < 5; ++r) {
            matbuf[wseg - 1][r * 5 + 0][lane] = M[r].a[0];
            matbuf[wseg - 1][r * 5 + 1][lane] = M[r].a[1];
            matbuf[wseg - 1][r * 5 + 2][lane] = M[r].b[0];
            matbuf[wseg - 1][r * 5 + 3][lane] = M[r].b[1];
            matbuf[wseg - 1][r * 5 + 4][lane] = M[r].e;
        }
    } else if (wseg == 0) {
        // ---- forward: carry0, site 0 (scalar), pairs 0..40 ----
        const v2f x01 = xr2[0];
        float cl[5], cn[5];
#pragma unroll
        for (int r = 0; r < 5; ++r)
            cl[r] = fmaf(x01[0], core_first[5 + r] - core_first[r], core_first[r]);
        const float* cm0 = cores_mid;             // site m=0
#pragma unroll
        for (int r = 0; r < 5; ++r) {
            float a = 0.f;
#pragma unroll
            for (int l = 0; l < 5; ++l) {
                float mm = fmaf(x01[1], cm0[l * 10 + 5 + r] - cm0[l * 10 + r],
                                cm0[l * 10 + r]);
                a = fmaf(cl[l], mm, a);
            }
            cn[r] = a;
        }
        fc.a = {cn[0], cn[1]}; fc.b = {cn[2], cn[3]}; fc.e = cn[4];
        const float* __restrict__ s = pk;
        C5 C;
#pragma unroll 1
        for (int p = 0; p < PFV; ++p) {
            const v2f xv = xr2[p + 1];
            buildC(s, xv[0], xv[1], C);
            fc = rowmul(fc, C);
            s += PKP;
        }
    } else {
        // ---- backward: vlast, site 781 (scalar), pairs 389..349 desc ----
        const v2f xz = xr2[391];                  // {x[782], x[783]}
        float vl[5], vn[5];
#pragma unroll
        for (int l = 0; l < 5; ++l)
            vl[l] = fmaf(xz[1], core_last[2 * l + 1] - core_last[2 * l],
                         core_last[2 * l]);
        const float* cmL = cores_mid + (size_t)781 * 50;   // site m=781
#pragma unroll
        for (int l = 0; l < 5; ++l) {
            float a = 0.f;
#pragma unroll
            for (int r = 0; r < 5; ++r) {
                float mm = fmaf(xz[0], cmL[l * 10 + 5 + r] - cmL[l * 10 + r],
                                cmL[l * 10 + r]);
                a = fmaf(mm, vl[r], a);
            }
            vn[l] = a;
        }
        R5 u; u.a = {vn[0], vn[1]}; u.b = {vn[2], vn[3]}; u.e = vn[4];
        const float* __restrict__ s = pk + (size_t)(NPAIR - 1) * PKP;
        C5 C;
#pragma unroll 1
        for (int p = NPAIR - 1; p >= BWD_P0; --p) {
            const v2f xv = xr2[p + 1];
            buildC(s, xv[0], xv[1], C);
            u = rowmul(u, C);          // stored C^T -> row form of column chain
            s -= PKP;
        }
        bv[0][lane] = u.a[0]; bv[1][lane] = u.a[1];
        bv[2][lane] = u.b[0]; bv[3][lane] = u.b[1];
        bv[4][lane] = u.e;
    }

    __syncthreads();

    if (wseg == 0) {
        // ---- combine: fc @ (seg1 .. seg14) . bv, then fc layer ----
        float cl[5] = {fc.a[0], fc.a[1], fc.b[0], fc.b[1], fc.e};
#pragma unroll 1
        for (int w2 = 0; w2 < 14; ++w2) {
            float v0[5];
#pragma unroll
            for (int r = 0; r < 5; ++r) v0[r] = cl[0] * matbuf[w2][r][lane];
#pragma unroll
            for (int l = 1; l < 5; ++l)
#pragma unroll
                for (int r = 0; r < 5; ++r)
                    v0[r] = fmaf(cl[l], matbuf[w2][l * 5 + r][lane], v0[r]);
#pragma unroll
            for (int r = 0; r < 5; ++r) cl[r] = v0[r];
        }
        float res = 0.f;
#pragma unroll
        for (int l = 0; l < 5; ++l) res = fmaf(cl[l], bv[l][lane], res);
        float* orow = out + (size_t)row * NOUT;
#pragma unroll
        for (int o = 0; o < NOUT; ++o) orow[o] = fmaf(res, fc_w[o], fc_b[o]);
    }
}

extern "C" void kernel_launch(void* const* d_in, const int* in_sizes, int n_in,
                              void* d_out, int out_size, void* d_ws, size_t ws_size,
                              hipStream_t stream) {
    const float* x          = (const float*)d_in[0];
    const float* core_first = (const float*)d_in[1];
    const float* cores_mid  = (const float*)d_in[2];
    const float* core_last  = (const float*)d_in[3];
    const float* fc_w       = (const float*)d_in[4];
    const float* fc_b       = (const float*)d_in[5];
    float* out              = (float*)d_out;
    float* pk               = (float*)d_ws;   // 390*112*4 = 174,720 B

    hipLaunchKernelGGL(prepack_pairs, dim3((NPAIR * 100 + 255) / 256), dim3(256),
                       0, stream, cores_mid, pk);
    hipLaunchKernelGGL(mps_pair_smem_kernel, dim3(Bn / 64), dim3(1024), 0, stream,
                       x, core_first, cores_mid, core_last, fc_w, fc_b, pk, out);
}